// Round 5
// baseline (233.289 us; speedup 1.0000x reference)
//
#include <hip/hip_runtime.h>

// CrossCompressUnit: rank-1 cross projections.
//   v_out = v * (e.w_vv) + e * (v.w_ev) + b_v
//   e_out = v * (e.w_ve) + e * (v.w_ee) + b_e
// B = 131072 rows, D = 128, f32. Demand 268 MB -> 42.6 us at 6.3 TB/s copy rate.
//
// Round 5: persistent waves + 2-stage software pipeline. Round-4 (nt loads/
// stores) removed the dirty-poison-eviction tax (80 -> ~64 us) but each wave
// still issued its 8 loads in one burst, waited, reduced, stored, and died --
// the memory pipe idles between bursts. Now each wave owns 4 spans of 8 rows
// and prefetches span i+1's 8 nt-loads while computing span i, keeping loads
// continuously in flight (compiler emits partial vmcnt waits).
// Layout: wave-contiguous -- load j covers rows {2j, 2j+1} of the span as one
// contiguous 1 KiB transaction (lanes 0-31 = row 2j, lanes 32-63 = row 2j+1).
// The xor<=16 butterfly stays within each 32-lane half, reducing each row
// independently; lane-local dot results line up exactly with the apply phase.

#define CCU_D 128
#define SPAN_ROWS 8                      // rows per wave per pipeline stage
#define F4_PER_SPAN (SPAN_ROWS * (CCU_D / 4))   // 256 float4 per span

typedef float f4 __attribute__((ext_vector_type(4)));

__device__ __forceinline__ float dot4v(const f4 a, const f4 b) {
    return a.x * b.x + a.y * b.y + a.z * b.z + a.w * b.w;
}

__global__ __launch_bounds__(256) void ccu_kernel(
    const float* __restrict__ v,
    const float* __restrict__ e,
    const float* __restrict__ w_vv,
    const float* __restrict__ w_ev,
    const float* __restrict__ w_ve,
    const float* __restrict__ w_ee,
    const float* __restrict__ b_v,
    const float* __restrict__ b_e,
    float* __restrict__ v_out,
    float* __restrict__ e_out,
    int nrows)
{
    const int lane   = threadIdx.x & 63;
    const int c      = lane & 31;                 // float4 column within row
    const int wid    = threadIdx.x >> 6;
    const int gwave  = (int)(blockIdx.x * (blockDim.x >> 6) + wid);
    const int nwaves = (int)(gridDim.x * (blockDim.x >> 6));
    const int nspans = nrows / SPAN_ROWS;         // 16384

    // Weights/biases: tiny + reused -> normal cached loads.
    const f4 wvv = ((const f4*)w_vv)[c];
    const f4 wev = ((const f4*)w_ev)[c];
    const f4 wve = ((const f4*)w_ve)[c];
    const f4 wee = ((const f4*)w_ee)[c];
    const f4 bv  = ((const f4*)b_v )[c];
    const f4 be  = ((const f4*)b_e )[c];

    const f4* __restrict__ vf  = (const f4*)v;
    const f4* __restrict__ ef  = (const f4*)e;
    f4* __restrict__ vof = (f4*)v_out;
    f4* __restrict__ eof = (f4*)e_out;

    int s = gwave;
    if (s >= nspans) return;

    f4 cv[4], ce[4], nv[4], ne[4];
    {
        const size_t base = (size_t)s * F4_PER_SPAN + lane;
        #pragma unroll
        for (int j = 0; j < 4; ++j) {
            cv[j] = __builtin_nontemporal_load(vf + base + j * 64);
            ce[j] = __builtin_nontemporal_load(ef + base + j * 64);
        }
    }

    while (true) {
        const int  sn   = s + nwaves;
        const bool more = (sn < nspans);

        // Prefetch next span: 8 nt-loads in flight during this span's compute.
        if (more) {
            const size_t nb = (size_t)sn * F4_PER_SPAN + lane;
            #pragma unroll
            for (int j = 0; j < 4; ++j) {
                nv[j] = __builtin_nontemporal_load(vf + nb + j * 64);
                ne[j] = __builtin_nontemporal_load(ef + nb + j * 64);
            }
        }

        // Per-lane partial dots for rows {2j + (lane>=32)}.
        float dvv[4], dev[4], dve[4], dee[4];
        #pragma unroll
        for (int j = 0; j < 4; ++j) {
            dvv[j] = dot4v(ce[j], wvv);
            dev[j] = dot4v(cv[j], wev);
            dve[j] = dot4v(ce[j], wve);
            dee[j] = dot4v(cv[j], wee);
        }

        // Butterfly over each 32-lane half (xor<=16 never crosses lane 32).
        #pragma unroll
        for (int off = 16; off >= 1; off >>= 1) {
            #pragma unroll
            for (int j = 0; j < 4; ++j) {
                dvv[j] += __shfl_xor(dvv[j], off);
                dev[j] += __shfl_xor(dev[j], off);
                dve[j] += __shfl_xor(dve[j], off);
                dee[j] += __shfl_xor(dee[j], off);
            }
        }

        // Apply + nt-store (issue stores per-j as soon as ready).
        const size_t ob = (size_t)s * F4_PER_SPAN + lane;
        #pragma unroll
        for (int j = 0; j < 4; ++j) {
            f4 vo, eo;
            vo.x = cv[j].x * dvv[j] + ce[j].x * dev[j] + bv.x;
            vo.y = cv[j].y * dvv[j] + ce[j].y * dev[j] + bv.y;
            vo.z = cv[j].z * dvv[j] + ce[j].z * dev[j] + bv.z;
            vo.w = cv[j].w * dvv[j] + ce[j].w * dev[j] + bv.w;

            eo.x = cv[j].x * dve[j] + ce[j].x * dee[j] + be.x;
            eo.y = cv[j].y * dve[j] + ce[j].y * dee[j] + be.y;
            eo.z = cv[j].z * dve[j] + ce[j].z * dee[j] + be.z;
            eo.w = cv[j].w * dve[j] + ce[j].w * dee[j] + be.w;

            __builtin_nontemporal_store(vo, vof + ob + j * 64);
            __builtin_nontemporal_store(eo, eof + ob + j * 64);
        }

        if (!more) break;
        s = sn;
        #pragma unroll
        for (int j = 0; j < 4; ++j) { cv[j] = nv[j]; ce[j] = ne[j]; }
    }
}

extern "C" void kernel_launch(void* const* d_in, const int* in_sizes, int n_in,
                              void* d_out, int out_size, void* d_ws, size_t ws_size,
                              hipStream_t stream) {
    const float* v    = (const float*)d_in[0];
    const float* e    = (const float*)d_in[1];
    const float* w_vv = (const float*)d_in[2];
    const float* w_ev = (const float*)d_in[3];
    const float* w_ve = (const float*)d_in[4];
    const float* w_ee = (const float*)d_in[5];
    const float* b_v  = (const float*)d_in[6];
    const float* b_e  = (const float*)d_in[7];

    const int nrows = in_sizes[0] / CCU_D;          // 131072
    float* v_out = (float*)d_out;
    float* e_out = (float*)d_out + (size_t)nrows * CCU_D;

    // 1024 blocks x 4 waves = 4096 persistent waves (4 blocks/CU, 16 waves/CU
    // at ~120 VGPR); nspans = 16384 -> exactly 4 pipelined spans per wave.
    const int blocks = 1024;
    ccu_kernel<<<blocks, 256, 0, stream>>>(v, e, w_vv, w_ev, w_ve, w_ee,
                                           b_v, b_e, v_out, e_out, nrows);
}